// Round 9
// baseline (336.808 us; speedup 1.0000x reference)
//
#include <hip/hip_runtime.h>
#include <stdint.h>
#include <math.h>

#define BATCH 32768
#define LDIM 128
#define HID 20

// ws layout (dword offsets):
//   WS_AW  u32 [m5][lane64][q4]   = 1280   A-fragments of Whh1 (f16 pairs)
//   WS_AU  u32 [ks2][lane64][q4]  = 512    A-fragments of W_ih2 (f16 pairs)
//   WS_WCD f32 [col127][grow80]   = 10160  W_ih1 cols, grow = 4*unit+type (f32 exact)
#define WS_AW  0
#define WS_AU  1280
#define WS_WCD 1792
#define WS_TOTAL 11952

// =====================================================================
// eps: jax.random.normal(key(42), (128,32768), f32), partitionable
// threefry (counters (0,n), output o0^o1) — VERIFIED PASSING. Do not touch.
// =====================================================================

__device__ __forceinline__ void threefry2x32(uint32_t x0, uint32_t x1,
                                             uint32_t& o0, uint32_t& o1) {
  const uint32_t k0 = 0u, k1 = 42u;
  const uint32_t k2 = k0 ^ k1 ^ 0x1BD11BDAu;
  uint32_t v0 = x0 + k0, v1 = x1 + k1;
#define TF_R(r) { v0 += v1; v1 = (v1 << (r)) | (v1 >> (32 - (r))); v1 ^= v0; }
  TF_R(13) TF_R(15) TF_R(26) TF_R(6)
  v0 += k1; v1 += k2 + 1u;
  TF_R(17) TF_R(29) TF_R(16) TF_R(24)
  v0 += k2; v1 += k0 + 2u;
  TF_R(13) TF_R(15) TF_R(26) TF_R(6)
  v0 += k0; v1 += k1 + 3u;
  TF_R(17) TF_R(29) TF_R(16) TF_R(24)
  v0 += k1; v1 += k2 + 4u;
  TF_R(13) TF_R(15) TF_R(26) TF_R(6)
  v0 += k2; v1 += k0 + 5u;
#undef TF_R
  o0 = v0; o1 = v1;
}

__device__ __forceinline__ float erfinv_xla_f32(float x) {
  float t = __fmul_rn(x, x);
  float w = -(float)log1p(-(double)t);   // correctly-rounded f32 log1p
  float p;
  if (w < 5.0f) {
    w = __fadd_rn(w, -2.5f);
    p = 2.81022636e-08f;
    p = __fadd_rn(__fmul_rn(p, w), 3.43273939e-07f);
    p = __fadd_rn(__fmul_rn(p, w), -3.5233877e-06f);
    p = __fadd_rn(__fmul_rn(p, w), -4.39150654e-06f);
    p = __fadd_rn(__fmul_rn(p, w), 0.00021858087f);
    p = __fadd_rn(__fmul_rn(p, w), -0.00125372503f);
    p = __fadd_rn(__fmul_rn(p, w), -0.00417768164f);
    p = __fadd_rn(__fmul_rn(p, w), 0.246640727f);
    p = __fadd_rn(__fmul_rn(p, w), 1.50140941f);
  } else {
    w = __fadd_rn(__fsqrt_rn(w), -3.0f);
    p = -0.000200214257f;
    p = __fadd_rn(__fmul_rn(p, w), 0.000100950558f);
    p = __fadd_rn(__fmul_rn(p, w), 0.00134934322f);
    p = __fadd_rn(__fmul_rn(p, w), -0.00367342844f);
    p = __fadd_rn(__fmul_rn(p, w), 0.00573950773f);
    p = __fadd_rn(__fmul_rn(p, w), -0.0076224613f);
    p = __fadd_rn(__fmul_rn(p, w), 0.00943887047f);
    p = __fadd_rn(__fmul_rn(p, w), 1.00167406f);
    p = __fadd_rn(__fmul_rn(p, w), 2.83297682f);
  }
  return __fmul_rn(p, x);
}

__device__ __forceinline__ float eps_val(int t, int b) {
  uint32_t n = (uint32_t)t * 32768u + (uint32_t)b;
  uint32_t o0, o1;
  threefry2x32(0u, n, o0, o1);
  uint32_t bits = o0 ^ o1;
  const float lo    = __uint_as_float(0xBF7FFFFFu);
  const float sqrt2 = __uint_as_float(0x3FB504F3u);
  float f = __fadd_rn(__uint_as_float((bits >> 9) | 0x3F800000u), -1.0f);
  float u = __fadd_rn(__fmul_rn(f, 2.0f), lo);
  u = fmaxf(u, lo);
  return __fmul_rn(sqrt2, erfinv_xla_f32(u));
}

__device__ __forceinline__ float fexp2(float x) { return __builtin_amdgcn_exp2f(x); }
__device__ __forceinline__ float frcp(float x)  { return __builtin_amdgcn_rcpf(x); }
__device__ __forceinline__ float fexp(float x)  { return fexp2(1.442695040888963f * x); }
__device__ __forceinline__ float sigm(float x)  { return frcp(1.0f + fexp2(-1.442695040888963f * x)); }
__device__ __forceinline__ float tanhx(float x) { return 1.0f - 2.0f * frcp(1.0f + fexp2(2.885390081777926f * x)); }

typedef _Float16 f16x8 __attribute__((ext_vector_type(8)));
typedef _Float16 f16x2 __attribute__((ext_vector_type(2)));
typedef float    f32x4 __attribute__((ext_vector_type(4)));

__device__ __forceinline__ uint32_t packh(float x, float y) {
  f16x2 p;
  p.x = (_Float16)x;
  p.y = (_Float16)y;
  return __builtin_bit_cast(uint32_t, p);
}

// =====================================================================
// repack: identical to r8 (verified passing). A/B same k-octet mapping so
// any k-permutation cancels; D layout m89-verified (col=lane&15,
// row=(lane>>4)*4+reg).
// =====================================================================
__global__ void repack_kernel(const float* __restrict__ W_ih1,
                              const float* __restrict__ W_hh1,
                              const float* __restrict__ W_ih2,
                              float* __restrict__ ws) {
  uint32_t* wsu = (uint32_t*)ws;
  const int stride = gridDim.x * blockDim.x;
  const int tid0 = blockIdx.x * blockDim.x + threadIdx.x;
  for (int idx = tid0; idx < 1280; idx += stride) {   // A_whh [m][l][q]
    int q = idx & 3, l = (idx >> 2) & 63, m = idx >> 8;
    int rA = l & 15, koct = l >> 4;
    int ty = rA & 3, u = 4 * m + (rA >> 2);
    int k0 = koct * 8 + 2 * q, k1 = k0 + 1;
    float w0 = (k0 < 20) ? W_hh1[(ty * 20 + u) * 20 + k0] : 0.0f;
    float w1 = (k1 < 20) ? W_hh1[(ty * 20 + u) * 20 + k1] : 0.0f;
    wsu[WS_AW + idx] = packh(w0, w1);
  }
  for (int idx = tid0; idx < 512; idx += stride) {    // A_u [ks][l][q]
    int q = idx & 3, l = (idx >> 2) & 63, ks = idx >> 8;
    int j = l & 15, koct = l >> 4;
    int kk0 = ks * 32 + koct * 8 + 2 * q, kk1 = kk0 + 1;
    float w0 = (j < 8 && kk0 < 40)
                   ? W_ih2[j * 40 + (kk0 & 1) * 20 + (kk0 >> 1)] : 0.0f;
    float w1 = (j < 8 && kk1 < 40)
                   ? W_ih2[j * 40 + (kk1 & 1) * 20 + (kk1 >> 1)] : 0.0f;
    wsu[WS_AU + idx] = packh(w0, w1);
  }
  for (int idx = tid0; idx < 10160; idx += stride) {  // Wc [col][grow]
    int grow = idx % 80, col = idx / 80;
    int u = grow >> 2, ty = grow & 3;
    ws[WS_WCD + idx] = W_ih1[(ty * 20 + u) * 127 + col];
  }
}

// V9 = r8 + LSTM2 software-pipelined one step behind.
// r8 post-mortem: 60% of the 5160 cy/step is stall; the same-step
// lrow write->read LDS round-trip (~120cy) + the LSTM2 MFMA/shuffle/
// 10-deep-transcendental chain sat on the critical path, yet nothing in
// step t+1's LSTM1 depends on LSTM2(t). Moving the LSTM2 finish to the
// TOP of the next iteration overlaps it with the independent acc-prefix
// and gates work. Pure schedule change: zero arithmetic reordering ->
// bit-identical output to r8 (absmax must stay 0.0859375).
__global__ __launch_bounds__(256, 1) void sampler_kernel(
    const float* __restrict__ mu, const float* __restrict__ log_var,
    const float* __restrict__ ws,
    const float* __restrict__ b_ih1, const float* __restrict__ b_hh1,
    const float* __restrict__ W_hh2,
    const float* __restrict__ b_ih2, const float* __restrict__ b_hh2,
    float* __restrict__ out) {
  __shared__ float WcL[10160];                       // [col][grow80] f32
  __shared__ __align__(16) _Float16 hsh[4][640];     // per wave: [elem16][40h]
  __shared__ __align__(16) _Float16 lsh[4][1152];    // per wave: [elem16][72h]

  const int tid  = threadIdx.x;
  const int lane = tid & 63;
  const int wvl  = __builtin_amdgcn_readfirstlane(tid >> 6);
  const int sub  = lane >> 4;                        // 0..3
  const int el   = lane & 15;
  const int elem = blockIdx.x * 64 + wvl * 16 + el;

  // stage Wc (f32, exact) + zero the exchange pads
  for (int i = tid; i < 10160; i += 256) WcL[i] = ws[WS_WCD + i];
  {
    uint32_t* hz = (uint32_t*)&hsh[0][0];
    for (int i = tid; i < 1280; i += 256) hz[i] = 0u;
    uint32_t* lz = (uint32_t*)&lsh[0][0];
    for (int i = tid; i < 2304; i += 256) lz[i] = 0u;
  }

  // A-fragments (constant across loop): coalesced 16B/lane global loads
  const uint32_t* wsu = (const uint32_t*)ws;
  f16x8 aw[5], au0, au1;
#pragma unroll
  for (int m = 0; m < 5; ++m)
    aw[m] = *(const f16x8*)(wsu + WS_AW + (m * 64 + lane) * 4);
  au0 = *(const f16x8*)(wsu + WS_AU + lane * 4);
  au1 = *(const f16x8*)(wsu + WS_AU + (64 + lane) * 4);

  __syncthreads();   // the only barrier: WcL + zero-init ready

  _Float16* hrow = &hsh[wvl][el * 40];               // 80B rows (16B-aligned)
  _Float16* lrow = &lsh[wvl][el * 72];               // 144B rows (16B-aligned)

  const float* mrow = mu + (size_t)elem * LDIM;

  // tiny LSTM2 weights: uniform scalar loads
  float w2[16], b2s[8];
#pragma unroll
  for (int i = 0; i < 16; ++i) w2[i] = W_hh2[i];
#pragma unroll
  for (int i = 0; i < 8; ++i)  b2s[i] = b_ih2[i] + b_hh2[i];

  // first_input (replicated on the 4 sub-lanes of each elem; bit-identical)
  float eps0 = eps_val(0, elem);
  float m0 = mrow[0];
  float fi = fmaf(eps0, fexp(0.5f * log_var[(size_t)elem * LDIM]), m0);

  // acc = C-operand of the gates MFMA: exact-f32 input-projection prefix.
  f32x4 acc[5];
#pragma unroll
  for (int m = 0; m < 5; ++m) {
    f32x4 w0 = *(const f32x4*)&WcL[16 * m + 4 * sub];
#pragma unroll
    for (int r = 0; r < 4; ++r) {
      const int grow = 16 * m + 4 * sub + r;
      const int g = (grow & 3) * 20 + (grow >> 2);
      acc[m][r] = fmaf(fi, w0[r], b_ih1[g] + b_hh1[g]);
    }
  }

  float cst[5];
#pragma unroll
  for (int m = 0; m < 5; ++m) cst[m] = 0.0f;
  float h2a = 0.0f, h2b = 0.0f, c2a = 0.0f, c2b = 0.0f;

  float* out_mu = out;
  float* out_lv = out + (size_t)BATCH * LDIM;
  float* out_sp = out + 2 * (size_t)BATCH * LDIM;
  const size_t rowoff = (size_t)elem * LDIM;
  if (sub == 0)      { out_mu[rowoff] = 0.0f; out_lv[rowoff] = 1.0f; }
  else if (sub == 1) { out_sp[rowoff] = fi; }

  const f32x4 z4 = {0.0f, 0.0f, 0.0f, 0.0f};
  float xm_pref = m0;
  float eps4 = 0.0f, eps_old = 0.0f;

  // LSTM2-finish for step e (reads lrow(e), updates h2/c2, stores row e).
  // Identical op sequence/order to r8's in-step block.
  auto lstm2_finish = [&](f16x8 bl0, f16x8 bl1, float eps_t, int e) {
    f32x4 d2 = __builtin_amdgcn_mfma_f32_16x16x32_f16(au0, bl0, z4, 0, 0, 0);
    d2 = __builtin_amdgcn_mfma_f32_16x16x32_f16(au1, bl1, d2, 0, 0, 0);
    float e0 = __shfl_xor(d2[0], 16, 64);
    float e1 = __shfl_xor(d2[1], 16, 64);
    float e2 = __shfl_xor(d2[2], 16, 64);
    float e3 = __shfl_xor(d2[3], 16, 64);
    const bool s1 = (sub == 1);
    float v0 = s1 ? e0 : d2[0], v1 = s1 ? e1 : d2[1];
    float v2 = s1 ? e2 : d2[2], v3 = s1 ? e3 : d2[3];
    float v4 = s1 ? d2[0] : e0, v5 = s1 ? d2[1] : e1;
    float v6 = s1 ? d2[2] : e2, v7 = s1 ? d2[3] : e3;

    float g0 = fmaf(h2a, w2[0],  fmaf(h2b, w2[1],  b2s[0])) + v0;
    float g1 = fmaf(h2a, w2[2],  fmaf(h2b, w2[3],  b2s[1])) + v1;
    float g2 = fmaf(h2a, w2[4],  fmaf(h2b, w2[5],  b2s[2])) + v2;
    float g3 = fmaf(h2a, w2[6],  fmaf(h2b, w2[7],  b2s[3])) + v3;
    float g4 = fmaf(h2a, w2[8],  fmaf(h2b, w2[9],  b2s[4])) + v4;
    float g5 = fmaf(h2a, w2[10], fmaf(h2b, w2[11], b2s[5])) + v5;
    float g6 = fmaf(h2a, w2[12], fmaf(h2b, w2[13], b2s[6])) + v6;
    float g7 = fmaf(h2a, w2[14], fmaf(h2b, w2[15], b2s[7])) + v7;

    float i20 = sigm(g0), i21 = sigm(g1);
    float f20 = sigm(g2), f21 = sigm(g3);
    float t20 = tanhx(g4), t21 = tanhx(g5);
    float o20 = sigm(g6), o21 = sigm(g7);
    c2a = fmaf(f20, c2a, i20 * t20);
    c2b = fmaf(f21, c2b, i21 * t21);
    h2a = o20 * tanhx(c2a);
    h2b = o21 * tanhx(c2b);

    if (sub == 0) {
      out_mu[rowoff + e] = h2a;
      out_lv[rowoff + e] = h2b;
    } else if (sub == 1) {
      out_sp[rowoff + e] = fmaf(eps_t, fexp(0.5f * h2b), h2a);
    }
  };

  for (int t = 1; t < LDIM; ++t) {
    float xm = xm_pref;
    xm_pref = mrow[t];

    // eps ring: refresh covers {t..t+3}; shadow the old window since the
    // pipelined consumer (e = t-1) is one step behind the producer.
    const bool refresh = ((t - 1) & 3) == 0;
    if (refresh) { eps_old = eps4; eps4 = eps_val(t + sub, elem); }

    // issue lrow(t-1) reads early: a full phase of independent work below
    // hides the LDS latency (this round's whole point).
    f16x8 bl0, bl1;
    if (t >= 2) {
      bl0 = *(const f16x8*)&lrow[sub * 8];
      bl1 = *(const f16x8*)&lrow[32 + sub * 8];
    }

    // ---- acc prefix (exact f32, r8-identical ordering) ----
    if (t >= 2) {
      if (t == 2) {
        float d0 = m0 - fi;   // col 0 switches first_input -> mu[:,0]
#pragma unroll
        for (int m = 0; m < 5; ++m) {
          f32x4 w0 = *(const f32x4*)&WcL[16 * m + 4 * sub];
#pragma unroll
          for (int r = 0; r < 4; ++r) acc[m][r] = fmaf(d0, w0[r], acc[m][r]);
        }
      }
#pragma unroll
      for (int m = 0; m < 5; ++m) {
        f32x4 wc = *(const f32x4*)&WcL[(t - 1) * 80 + 16 * m + 4 * sub];
#pragma unroll
        for (int r = 0; r < 4; ++r) acc[m][r] = fmaf(xm, wc[r], acc[m][r]);
      }
    }

    // ---- LSTM2 finish for e = t-1 (pipelined, off the LSTM1 path) ----
    if (t >= 2) {
      // slot (t-2)&3 is correct in both windows; source flips on refresh
      float src = refresh ? eps_old : eps4;
      float eps_t = __shfl(src, ((t - 2) & 3) * 16 + el, 64);
      lstm2_finish(bl0, bl1, eps_t, t - 1);
    }

    // ---- gates = Whh @ h^T + acc : 5 MFMA ----
    f16x8 bh = *(const f16x8*)&hrow[sub * 8];        // h(t-1), written last iter
    f32x4 d[5];
#pragma unroll
    for (int m = 0; m < 5; ++m)
      d[m] = __builtin_amdgcn_mfma_f32_16x16x32_f16(aw[m], bh, acc[m], 0, 0, 0);

    // ---- activations + cell (lane owns unit 4m+sub, all 4 types) ----
#pragma unroll
    for (int m = 0; m < 5; ++m) {
      float ik = sigm(d[m][0]), fk = sigm(d[m][1]);
      float gk = tanhx(d[m][2]), ok = sigm(d[m][3]);
      float cn = fmaf(fk, cst[m], ik * gk);
      cst[m] = cn;
      float hk = ok * tanhx(cn);
      hrow[4 * m + sub] = (_Float16)hk;              // h for next step's B
      float lh = (hk >= 0.0f) ? hk : 0.01f * hk;
      float lc = (cn >= 0.0f) ? cn : 0.01f * cn;
      f16x2 p; p.x = (_Float16)lh; p.y = (_Float16)lc;
      ((f16x2*)lrow)[4 * m + sub] = p;               // consumed next iter
    }
  }

  // ---- drain: LSTM2 finish for e = 127 ----
  {
    f16x8 bl0 = *(const f16x8*)&lrow[sub * 8];
    f16x8 bl1 = *(const f16x8*)&lrow[32 + sub * 8];
    float eps_t = eps_val(127, elem);   // one direct call; bit-identical
    lstm2_finish(bl0, bl1, eps_t, 127);
  }
}

extern "C" void kernel_launch(void* const* d_in, const int* in_sizes, int n_in,
                              void* d_out, int out_size, void* d_ws, size_t ws_size,
                              hipStream_t stream) {
  (void)in_sizes; (void)n_in; (void)ws_size; (void)out_size;
  const float* mu      = (const float*)d_in[0];
  const float* log_var = (const float*)d_in[1];
  const float* W_ih1   = (const float*)d_in[2];
  const float* W_hh1   = (const float*)d_in[3];
  const float* b_ih1   = (const float*)d_in[4];
  const float* b_hh1   = (const float*)d_in[5];
  const float* W_ih2   = (const float*)d_in[6];
  const float* W_hh2   = (const float*)d_in[7];
  const float* b_ih2   = (const float*)d_in[8];
  const float* b_hh2   = (const float*)d_in[9];
  float* out = (float*)d_out;
  float* ws  = (float*)d_ws;   // needs 11952 dwords = 47.8 KB

  repack_kernel<<<dim3(8), dim3(256), 0, stream>>>(W_ih1, W_hh1, W_ih2, ws);
  dim3 grid(BATCH / 64), block(256);   // 4 waves/block, 16 elems/wave
  sampler_kernel<<<grid, block, 0, stream>>>(mu, log_var, ws, b_ih1, b_hh1,
                                             W_hh2, b_ih2, b_hh2, out);
}

// Round 10
// 312.231 us; speedup vs baseline: 1.0787x; 1.0787x over previous
//
#include <hip/hip_runtime.h>
#include <stdint.h>
#include <math.h>

#define BATCH 32768
#define LDIM 128
#define HID 20

// ws layout (dword offsets):
//   WS_AW  u32 [m5][lane64][q4]   = 1280   A-fragments of Whh1 (f16 pairs)
//   WS_AU  u32 [ks2][lane64][q4]  = 512    A-fragments of W_ih2 (f16 pairs)
//   WS_WCD f32 [col127][grow80]   = 10160  W_ih1 cols, grow = 4*unit+type (f32 exact)
#define WS_AW  0
#define WS_AU  1280
#define WS_WCD 1792
#define WS_TOTAL 11952

// =====================================================================
// eps: jax.random.normal(key(42), (128,32768), f32), partitionable
// threefry (counters (0,n), output o0^o1) — VERIFIED PASSING. Do not touch.
// =====================================================================

__device__ __forceinline__ void threefry2x32(uint32_t x0, uint32_t x1,
                                             uint32_t& o0, uint32_t& o1) {
  const uint32_t k0 = 0u, k1 = 42u;
  const uint32_t k2 = k0 ^ k1 ^ 0x1BD11BDAu;
  uint32_t v0 = x0 + k0, v1 = x1 + k1;
#define TF_R(r) { v0 += v1; v1 = (v1 << (r)) | (v1 >> (32 - (r))); v1 ^= v0; }
  TF_R(13) TF_R(15) TF_R(26) TF_R(6)
  v0 += k1; v1 += k2 + 1u;
  TF_R(17) TF_R(29) TF_R(16) TF_R(24)
  v0 += k2; v1 += k0 + 2u;
  TF_R(13) TF_R(15) TF_R(26) TF_R(6)
  v0 += k0; v1 += k1 + 3u;
  TF_R(17) TF_R(29) TF_R(16) TF_R(24)
  v0 += k1; v1 += k2 + 4u;
  TF_R(13) TF_R(15) TF_R(26) TF_R(6)
  v0 += k2; v1 += k0 + 5u;
#undef TF_R
  o0 = v0; o1 = v1;
}

__device__ __forceinline__ float erfinv_xla_f32(float x) {
  float t = __fmul_rn(x, x);
  float w = -(float)log1p(-(double)t);   // correctly-rounded f32 log1p
  float p;
  if (w < 5.0f) {
    w = __fadd_rn(w, -2.5f);
    p = 2.81022636e-08f;
    p = __fadd_rn(__fmul_rn(p, w), 3.43273939e-07f);
    p = __fadd_rn(__fmul_rn(p, w), -3.5233877e-06f);
    p = __fadd_rn(__fmul_rn(p, w), -4.39150654e-06f);
    p = __fadd_rn(__fmul_rn(p, w), 0.00021858087f);
    p = __fadd_rn(__fmul_rn(p, w), -0.00125372503f);
    p = __fadd_rn(__fmul_rn(p, w), -0.00417768164f);
    p = __fadd_rn(__fmul_rn(p, w), 0.246640727f);
    p = __fadd_rn(__fmul_rn(p, w), 1.50140941f);
  } else {
    w = __fadd_rn(__fsqrt_rn(w), -3.0f);
    p = -0.000200214257f;
    p = __fadd_rn(__fmul_rn(p, w), 0.000100950558f);
    p = __fadd_rn(__fmul_rn(p, w), 0.00134934322f);
    p = __fadd_rn(__fmul_rn(p, w), -0.00367342844f);
    p = __fadd_rn(__fmul_rn(p, w), 0.00573950773f);
    p = __fadd_rn(__fmul_rn(p, w), -0.0076224613f);
    p = __fadd_rn(__fmul_rn(p, w), 0.00943887047f);
    p = __fadd_rn(__fmul_rn(p, w), 1.00167406f);
    p = __fadd_rn(__fmul_rn(p, w), 2.83297682f);
  }
  return __fmul_rn(p, x);
}

__device__ __forceinline__ float eps_val(int t, int b) {
  uint32_t n = (uint32_t)t * 32768u + (uint32_t)b;
  uint32_t o0, o1;
  threefry2x32(0u, n, o0, o1);
  uint32_t bits = o0 ^ o1;
  const float lo    = __uint_as_float(0xBF7FFFFFu);
  const float sqrt2 = __uint_as_float(0x3FB504F3u);
  float f = __fadd_rn(__uint_as_float((bits >> 9) | 0x3F800000u), -1.0f);
  float u = __fadd_rn(__fmul_rn(f, 2.0f), lo);
  u = fmaxf(u, lo);
  return __fmul_rn(sqrt2, erfinv_xla_f32(u));
}

__device__ __forceinline__ float fexp2(float x) { return __builtin_amdgcn_exp2f(x); }
__device__ __forceinline__ float frcp(float x)  { return __builtin_amdgcn_rcpf(x); }
__device__ __forceinline__ float fexp(float x)  { return fexp2(1.442695040888963f * x); }
__device__ __forceinline__ float sigm(float x)  { return frcp(1.0f + fexp2(-1.442695040888963f * x)); }
__device__ __forceinline__ float tanhx(float x) { return 1.0f - 2.0f * frcp(1.0f + fexp2(2.885390081777926f * x)); }

typedef _Float16 f16x8 __attribute__((ext_vector_type(8)));
typedef _Float16 f16x2 __attribute__((ext_vector_type(2)));
typedef float    f32x4 __attribute__((ext_vector_type(4)));

__device__ __forceinline__ uint32_t packh(float x, float y) {
  f16x2 p;
  p.x = (_Float16)x;
  p.y = (_Float16)y;
  return __builtin_bit_cast(uint32_t, p);
}

// =====================================================================
// repack: identical to r8/r9 (verified passing). A/B same k-octet mapping
// so any k-permutation cancels; D layout m89-verified (col=lane&15,
// row=(lane>>4)*4+reg).
// =====================================================================
__global__ void repack_kernel(const float* __restrict__ W_ih1,
                              const float* __restrict__ W_hh1,
                              const float* __restrict__ W_ih2,
                              float* __restrict__ ws) {
  uint32_t* wsu = (uint32_t*)ws;
  const int stride = gridDim.x * blockDim.x;
  const int tid0 = blockIdx.x * blockDim.x + threadIdx.x;
  for (int idx = tid0; idx < 1280; idx += stride) {   // A_whh [m][l][q]
    int q = idx & 3, l = (idx >> 2) & 63, m = idx >> 8;
    int rA = l & 15, koct = l >> 4;
    int ty = rA & 3, u = 4 * m + (rA >> 2);
    int k0 = koct * 8 + 2 * q, k1 = k0 + 1;
    float w0 = (k0 < 20) ? W_hh1[(ty * 20 + u) * 20 + k0] : 0.0f;
    float w1 = (k1 < 20) ? W_hh1[(ty * 20 + u) * 20 + k1] : 0.0f;
    wsu[WS_AW + idx] = packh(w0, w1);
  }
  for (int idx = tid0; idx < 512; idx += stride) {    // A_u [ks][l][q]
    int q = idx & 3, l = (idx >> 2) & 63, ks = idx >> 8;
    int j = l & 15, koct = l >> 4;
    int kk0 = ks * 32 + koct * 8 + 2 * q, kk1 = kk0 + 1;
    float w0 = (j < 8 && kk0 < 40)
                   ? W_ih2[j * 40 + (kk0 & 1) * 20 + (kk0 >> 1)] : 0.0f;
    float w1 = (j < 8 && kk1 < 40)
                   ? W_ih2[j * 40 + (kk1 & 1) * 20 + (kk1 >> 1)] : 0.0f;
    wsu[WS_AU + idx] = packh(w0, w1);
  }
  for (int idx = tid0; idx < 10160; idx += stride) {  // Wc [col][grow]
    int grow = idx % 80, col = idx / 80;
    int u = grow >> 2, ty = grow & 3;
    ws[WS_WCD + idx] = W_ih1[(ty * 20 + u) * 127 + col];
  }
}

// V10 = r9 + LSTM2 sub-split (de-replication).
// r9 post-mortem: issue-bound (VALUBusy 77% == op-count model). The LSTM2
// tail was replicated on all 4 subs although the d2 MFMA already splits
// the 8 gate pre-activations across sub0 (j0-3) / sub1 (j4-7). Each lane
// now activates only its own 4 rows via the branchless unified form
// act = fmaf(B, rcp(1+exp2(S*g)), A)  (bit-identical to sigm/tanhx), then
// ONE shfl_xor(16) per value exchanges the activated gates. Saves ~36
// VALU + 8 trans per wave-step. All other FP order unchanged -> output
// bit-identical to r8/r9 (absmax must stay 0.0859375).
__global__ __launch_bounds__(256, 1) void sampler_kernel(
    const float* __restrict__ mu, const float* __restrict__ log_var,
    const float* __restrict__ ws,
    const float* __restrict__ b_ih1, const float* __restrict__ b_hh1,
    const float* __restrict__ W_hh2,
    const float* __restrict__ b_ih2, const float* __restrict__ b_hh2,
    float* __restrict__ out) {
  __shared__ float WcL[10160];                       // [col][grow80] f32
  __shared__ __align__(16) _Float16 hsh[4][640];     // per wave: [elem16][40h]
  __shared__ __align__(16) _Float16 lsh[4][1152];    // per wave: [elem16][72h]

  const int tid  = threadIdx.x;
  const int lane = tid & 63;
  const int wvl  = __builtin_amdgcn_readfirstlane(tid >> 6);
  const int sub  = lane >> 4;                        // 0..3
  const int el   = lane & 15;
  const int elem = blockIdx.x * 64 + wvl * 16 + el;

  // stage Wc (f32, exact) + zero the exchange pads
  for (int i = tid; i < 10160; i += 256) WcL[i] = ws[WS_WCD + i];
  {
    uint32_t* hz = (uint32_t*)&hsh[0][0];
    for (int i = tid; i < 1280; i += 256) hz[i] = 0u;
    uint32_t* lz = (uint32_t*)&lsh[0][0];
    for (int i = tid; i < 2304; i += 256) lz[i] = 0u;
  }

  // A-fragments (constant across loop): coalesced 16B/lane global loads
  const uint32_t* wsu = (const uint32_t*)ws;
  f16x8 aw[5], au0, au1;
#pragma unroll
  for (int m = 0; m < 5; ++m)
    aw[m] = *(const f16x8*)(wsu + WS_AW + (m * 64 + lane) * 4);
  au0 = *(const f16x8*)(wsu + WS_AU + lane * 4);
  au1 = *(const f16x8*)(wsu + WS_AU + (64 + lane) * 4);

  __syncthreads();   // the only barrier: WcL + zero-init ready

  _Float16* hrow = &hsh[wvl][el * 40];               // 80B rows (16B-aligned)
  _Float16* lrow = &lsh[wvl][el * 72];               // 144B rows (16B-aligned)

  const float* mrow = mu + (size_t)elem * LDIM;

  // per-lane LSTM2 constants for MY 4 d2 rows j = 4*sub + r (&7 aliases
  // the garbage sub2/3 lanes into range; their whole LSTM2 chain is
  // garbage-but-unread, same as r8/r9). Static r-indexing -> registers.
  float wa[4], wb[4], bb2[4], Sc[4], Ac[4], Bc[4];
#pragma unroll
  for (int r = 0; r < 4; ++r) {
    const int j = (4 * sub + r) & 7;
    wa[r]  = W_hh2[2 * j];
    wb[r]  = W_hh2[2 * j + 1];
    bb2[r] = b_ih2[j] + b_hh2[j];
    const bool isT = (j == 4) || (j == 5);           // t20,t21 are tanh
    Sc[r] = isT ?  2.885390081777926f : -1.442695040888963f;
    Ac[r] = isT ?  1.0f : 0.0f;
    Bc[r] = isT ? -2.0f : 1.0f;
  }

  // first_input (replicated on the 4 sub-lanes of each elem; bit-identical)
  float eps0 = eps_val(0, elem);
  float m0 = mrow[0];
  float fi = fmaf(eps0, fexp(0.5f * log_var[(size_t)elem * LDIM]), m0);

  // acc = C-operand of the gates MFMA: exact-f32 input-projection prefix.
  f32x4 acc[5];
#pragma unroll
  for (int m = 0; m < 5; ++m) {
    f32x4 w0 = *(const f32x4*)&WcL[16 * m + 4 * sub];
#pragma unroll
    for (int r = 0; r < 4; ++r) {
      const int grow = 16 * m + 4 * sub + r;
      const int g = (grow & 3) * 20 + (grow >> 2);
      acc[m][r] = fmaf(fi, w0[r], b_ih1[g] + b_hh1[g]);
    }
  }

  float cst[5];
#pragma unroll
  for (int m = 0; m < 5; ++m) cst[m] = 0.0f;
  float h2a = 0.0f, h2b = 0.0f, c2a = 0.0f, c2b = 0.0f;

  float* out_mu = out;
  float* out_lv = out + (size_t)BATCH * LDIM;
  float* out_sp = out + 2 * (size_t)BATCH * LDIM;
  const size_t rowoff = (size_t)elem * LDIM;
  if (sub == 0)      { out_mu[rowoff] = 0.0f; out_lv[rowoff] = 1.0f; }
  else if (sub == 1) { out_sp[rowoff] = fi; }

  const f32x4 z4 = {0.0f, 0.0f, 0.0f, 0.0f};
  float xm_pref = m0;
  float eps4 = 0.0f, eps_old = 0.0f;

  // LSTM2-finish for step e: sub-split gates. My 4 g's from my d2 rows;
  // activate with unified branchless form (bit-identical to sigm/tanhx:
  // fma(1,x,0)=x, and 1-2r == fma(-2,r,1) since 2r is exact); exchange
  // ACTIVATED values with one xor-16 shuffle each.
  auto lstm2_finish = [&](f16x8 bl0, f16x8 bl1, float eps_t, int e) {
    f32x4 d2 = __builtin_amdgcn_mfma_f32_16x16x32_f16(au0, bl0, z4, 0, 0, 0);
    d2 = __builtin_amdgcn_mfma_f32_16x16x32_f16(au1, bl1, d2, 0, 0, 0);
    float act[4];
#pragma unroll
    for (int r = 0; r < 4; ++r) {
      float g  = fmaf(h2a, wa[r], fmaf(h2b, wb[r], bb2[r])) + d2[r];
      float rc = frcp(1.0f + fexp2(Sc[r] * g));
      act[r] = fmaf(Bc[r], rc, Ac[r]);
    }
    float x0 = __shfl_xor(act[0], 16, 64);
    float x1 = __shfl_xor(act[1], 16, 64);
    float x2 = __shfl_xor(act[2], 16, 64);
    float x3 = __shfl_xor(act[3], 16, 64);
    const bool s1 = (sub & 1);
    float i20 = s1 ? x0 : act[0], i21 = s1 ? x1 : act[1];
    float f20 = s1 ? x2 : act[2], f21 = s1 ? x3 : act[3];
    float t20 = s1 ? act[0] : x0, t21 = s1 ? act[1] : x1;
    float o20 = s1 ? act[2] : x2, o21 = s1 ? act[3] : x3;
    c2a = fmaf(f20, c2a, i20 * t20);
    c2b = fmaf(f21, c2b, i21 * t21);
    h2a = o20 * tanhx(c2a);
    h2b = o21 * tanhx(c2b);
    if (sub == 0) {
      out_mu[rowoff + e] = h2a;
      out_lv[rowoff + e] = h2b;
    } else if (sub == 1) {
      out_sp[rowoff + e] = fmaf(eps_t, fexp(0.5f * h2b), h2a);
    }
  };

  for (int t = 1; t < LDIM; ++t) {
    float xm = xm_pref;
    xm_pref = mrow[t];

    // eps ring: refresh covers {t..t+3}; shadow the old window since the
    // pipelined consumer (e = t-1) is one step behind the producer.
    const bool refresh = ((t - 1) & 3) == 0;
    if (refresh) { eps_old = eps4; eps4 = eps_val(t + sub, elem); }

    // issue lrow(t-1) reads early: a full phase of independent work below
    // hides the LDS latency (r9's pipeline, kept).
    f16x8 bl0, bl1;
    if (t >= 2) {
      bl0 = *(const f16x8*)&lrow[sub * 8];
      bl1 = *(const f16x8*)&lrow[32 + sub * 8];
    }

    // ---- acc prefix (exact f32, r9-identical ordering) ----
    if (t >= 2) {
      if (t == 2) {
        float d0 = m0 - fi;   // col 0 switches first_input -> mu[:,0]
#pragma unroll
        for (int m = 0; m < 5; ++m) {
          f32x4 w0 = *(const f32x4*)&WcL[16 * m + 4 * sub];
#pragma unroll
          for (int r = 0; r < 4; ++r) acc[m][r] = fmaf(d0, w0[r], acc[m][r]);
        }
      }
#pragma unroll
      for (int m = 0; m < 5; ++m) {
        f32x4 wc = *(const f32x4*)&WcL[(t - 1) * 80 + 16 * m + 4 * sub];
#pragma unroll
        for (int r = 0; r < 4; ++r) acc[m][r] = fmaf(xm, wc[r], acc[m][r]);
      }
    }

    // ---- LSTM2 finish for e = t-1 (pipelined, off the LSTM1 path) ----
    if (t >= 2) {
      float src = refresh ? eps_old : eps4;
      float eps_t = __shfl(src, ((t - 2) & 3) * 16 + el, 64);
      lstm2_finish(bl0, bl1, eps_t, t - 1);
    }

    // ---- gates = Whh @ h^T + acc : 5 MFMA ----
    f16x8 bh = *(const f16x8*)&hrow[sub * 8];        // h(t-1), written last iter
    f32x4 d[5];
#pragma unroll
    for (int m = 0; m < 5; ++m)
      d[m] = __builtin_amdgcn_mfma_f32_16x16x32_f16(aw[m], bh, acc[m], 0, 0, 0);

    // ---- activations + cell (lane owns unit 4m+sub, all 4 types) ----
#pragma unroll
    for (int m = 0; m < 5; ++m) {
      float ik = sigm(d[m][0]), fk = sigm(d[m][1]);
      float gk = tanhx(d[m][2]), ok = sigm(d[m][3]);
      float cn = fmaf(fk, cst[m], ik * gk);
      cst[m] = cn;
      float hk = ok * tanhx(cn);
      hrow[4 * m + sub] = (_Float16)hk;              // h for next step's B
      float lh = (hk >= 0.0f) ? hk : 0.01f * hk;
      float lc = (cn >= 0.0f) ? cn : 0.01f * cn;
      f16x2 p; p.x = (_Float16)lh; p.y = (_Float16)lc;
      ((f16x2*)lrow)[4 * m + sub] = p;               // consumed next iter
    }
  }

  // ---- drain: LSTM2 finish for e = 127 ----
  {
    f16x8 bl0 = *(const f16x8*)&lrow[sub * 8];
    f16x8 bl1 = *(const f16x8*)&lrow[32 + sub * 8];
    float eps_t = eps_val(127, elem);   // one direct call; bit-identical
    lstm2_finish(bl0, bl1, eps_t, 127);
  }
}

extern "C" void kernel_launch(void* const* d_in, const int* in_sizes, int n_in,
                              void* d_out, int out_size, void* d_ws, size_t ws_size,
                              hipStream_t stream) {
  (void)in_sizes; (void)n_in; (void)ws_size; (void)out_size;
  const float* mu      = (const float*)d_in[0];
  const float* log_var = (const float*)d_in[1];
  const float* W_ih1   = (const float*)d_in[2];
  const float* W_hh1   = (const float*)d_in[3];
  const float* b_ih1   = (const float*)d_in[4];
  const float* b_hh1   = (const float*)d_in[5];
  const float* W_ih2   = (const float*)d_in[6];
  const float* W_hh2   = (const float*)d_in[7];
  const float* b_ih2   = (const float*)d_in[8];
  const float* b_hh2   = (const float*)d_in[9];
  float* out = (float*)d_out;
  float* ws  = (float*)d_ws;   // needs 11952 dwords = 47.8 KB

  repack_kernel<<<dim3(8), dim3(256), 0, stream>>>(W_ih1, W_hh1, W_ih2, ws);
  dim3 grid(BATCH / 64), block(256);   // 4 waves/block, 16 elems/wave
  sampler_kernel<<<grid, block, 0, stream>>>(mu, log_var, ws, b_ih1, b_hh1,
                                             W_hh2, b_ih2, b_hh2, out);
}

// Round 11
// 305.249 us; speedup vs baseline: 1.1034x; 1.0229x over previous
//
#include <hip/hip_runtime.h>
#include <stdint.h>
#include <math.h>

#define BATCH 32768
#define LDIM 128
#define HID 20

// ws layout (dword offsets):
//   WS_AW  u32 [m5][lane64][q4]   = 1280   A-fragments of Whh1 (f16 pairs)
//   WS_AU  u32 [ks2][lane64][q4]  = 512    A-fragments of W_ih2 (f16 pairs)
//   WS_WCD f32 [col127][grow80]   = 10160  W_ih1 cols, grow = 4*unit+type (f32 exact)
#define WS_AW  0
#define WS_AU  1280
#define WS_WCD 1792
#define WS_TOTAL 11952

// =====================================================================
// eps: jax.random.normal(key(42), (128,32768), f32), partitionable
// threefry (counters (0,n), output o0^o1) — VERIFIED PASSING. Do not touch.
// =====================================================================

__device__ __forceinline__ void threefry2x32(uint32_t x0, uint32_t x1,
                                             uint32_t& o0, uint32_t& o1) {
  const uint32_t k0 = 0u, k1 = 42u;
  const uint32_t k2 = k0 ^ k1 ^ 0x1BD11BDAu;
  uint32_t v0 = x0 + k0, v1 = x1 + k1;
#define TF_R(r) { v0 += v1; v1 = (v1 << (r)) | (v1 >> (32 - (r))); v1 ^= v0; }
  TF_R(13) TF_R(15) TF_R(26) TF_R(6)
  v0 += k1; v1 += k2 + 1u;
  TF_R(17) TF_R(29) TF_R(16) TF_R(24)
  v0 += k2; v1 += k0 + 2u;
  TF_R(13) TF_R(15) TF_R(26) TF_R(6)
  v0 += k0; v1 += k1 + 3u;
  TF_R(17) TF_R(29) TF_R(16) TF_R(24)
  v0 += k1; v1 += k2 + 4u;
  TF_R(13) TF_R(15) TF_R(26) TF_R(6)
  v0 += k2; v1 += k0 + 5u;
#undef TF_R
  o0 = v0; o1 = v1;
}

__device__ __forceinline__ float erfinv_xla_f32(float x) {
  float t = __fmul_rn(x, x);
  float w = -(float)log1p(-(double)t);   // correctly-rounded f32 log1p
  float p;
  if (w < 5.0f) {
    w = __fadd_rn(w, -2.5f);
    p = 2.81022636e-08f;
    p = __fadd_rn(__fmul_rn(p, w), 3.43273939e-07f);
    p = __fadd_rn(__fmul_rn(p, w), -3.5233877e-06f);
    p = __fadd_rn(__fmul_rn(p, w), -4.39150654e-06f);
    p = __fadd_rn(__fmul_rn(p, w), 0.00021858087f);
    p = __fadd_rn(__fmul_rn(p, w), -0.00125372503f);
    p = __fadd_rn(__fmul_rn(p, w), -0.00417768164f);
    p = __fadd_rn(__fmul_rn(p, w), 0.246640727f);
    p = __fadd_rn(__fmul_rn(p, w), 1.50140941f);
  } else {
    w = __fadd_rn(__fsqrt_rn(w), -3.0f);
    p = -0.000200214257f;
    p = __fadd_rn(__fmul_rn(p, w), 0.000100950558f);
    p = __fadd_rn(__fmul_rn(p, w), 0.00134934322f);
    p = __fadd_rn(__fmul_rn(p, w), -0.00367342844f);
    p = __fadd_rn(__fmul_rn(p, w), 0.00573950773f);
    p = __fadd_rn(__fmul_rn(p, w), -0.0076224613f);
    p = __fadd_rn(__fmul_rn(p, w), 0.00943887047f);
    p = __fadd_rn(__fmul_rn(p, w), 1.00167406f);
    p = __fadd_rn(__fmul_rn(p, w), 2.83297682f);
  }
  return __fmul_rn(p, x);
}

__device__ __forceinline__ float eps_val(int t, int b) {
  uint32_t n = (uint32_t)t * 32768u + (uint32_t)b;
  uint32_t o0, o1;
  threefry2x32(0u, n, o0, o1);
  uint32_t bits = o0 ^ o1;
  const float lo    = __uint_as_float(0xBF7FFFFFu);
  const float sqrt2 = __uint_as_float(0x3FB504F3u);
  float f = __fadd_rn(__uint_as_float((bits >> 9) | 0x3F800000u), -1.0f);
  float u = __fadd_rn(__fmul_rn(f, 2.0f), lo);
  u = fmaxf(u, lo);
  return __fmul_rn(sqrt2, erfinv_xla_f32(u));
}

__device__ __forceinline__ float fexp2(float x) { return __builtin_amdgcn_exp2f(x); }
__device__ __forceinline__ float frcp(float x)  { return __builtin_amdgcn_rcpf(x); }
__device__ __forceinline__ float fexp(float x)  { return fexp2(1.442695040888963f * x); }
__device__ __forceinline__ float sigm(float x)  { return frcp(1.0f + fexp2(-1.442695040888963f * x)); }
__device__ __forceinline__ float tanhx(float x) { return 1.0f - 2.0f * frcp(1.0f + fexp2(2.885390081777926f * x)); }

typedef _Float16 f16x8 __attribute__((ext_vector_type(8)));
typedef _Float16 f16x2 __attribute__((ext_vector_type(2)));
typedef float    f32x4 __attribute__((ext_vector_type(4)));
typedef uint32_t u32x4 __attribute__((ext_vector_type(4)));

__device__ __forceinline__ uint32_t packh(float x, float y) {
  f16x2 p;
  p.x = (_Float16)x;
  p.y = (_Float16)y;
  return __builtin_bit_cast(uint32_t, p);
}

// =====================================================================
// repack (V11): k-slot mapping CO-DESIGNED with the D-layout so the B
// operands are register-resident (zero LDS h/lhlc exchange).
//   gates MFMA: B lane (sub,el) k-slot sub*8+m  <-> h of unit 4m+sub
//               (m=0..4 real, 5..7 zero) = the lane's OWN D-output units.
//   LSTM2 MFMA: B k-slot ks*32 + sub*8 + q <-> (m=ks*4+(q>>1), s=q&1),
//               value = {lh,lc}[s] of unit 4m+sub (m<5 real, else zero).
// A is repacked with the SAME k-mapping, so the permutation cancels
// (only the MFMA-internal summation order changes: few-ulp wiggle).
// D layout m89-verified (col=lane&15, row=(lane>>4)*4+reg).
// =====================================================================
__global__ void repack_kernel(const float* __restrict__ W_ih1,
                              const float* __restrict__ W_hh1,
                              const float* __restrict__ W_ih2,
                              float* __restrict__ ws) {
  uint32_t* wsu = (uint32_t*)ws;
  const int stride = gridDim.x * blockDim.x;
  const int tid0 = blockIdx.x * blockDim.x + threadIdx.x;
  for (int idx = tid0; idx < 1280; idx += stride) {   // A_whh [m][l][q]
    int q = idx & 3, l = (idx >> 2) & 63, m = idx >> 8;
    int rA = l & 15, koct = l >> 4;
    int ty = rA & 3, u = 4 * m + (rA >> 2);
    int k0 = koct * 8 + 2 * q, k1 = k0 + 1;
    int mm0 = k0 & 7, mm1 = k1 & 7;                   // k-slot within octet
    float w0 = (mm0 < 5) ? W_hh1[(ty * 20 + u) * 20 + (4 * mm0 + koct)] : 0.0f;
    float w1 = (mm1 < 5) ? W_hh1[(ty * 20 + u) * 20 + (4 * mm1 + koct)] : 0.0f;
    wsu[WS_AW + idx] = packh(w0, w1);
  }
  for (int idx = tid0; idx < 512; idx += stride) {    // A_u [ks][l][q]
    int q = idx & 3, l = (idx >> 2) & 63, ks = idx >> 8;
    int j = l & 15, koct = l >> 4;
    int qq0 = 2 * q, qq1 = 2 * q + 1;                 // slot within octet
    int mr0 = ks * 4 + (qq0 >> 1), mr1 = ks * 4 + (qq1 >> 1);
    float w0 = (j < 8 && mr0 < 5)
                   ? W_ih2[j * 40 + (qq0 & 1) * 20 + (4 * mr0 + koct)] : 0.0f;
    float w1 = (j < 8 && mr1 < 5)
                   ? W_ih2[j * 40 + (qq1 & 1) * 20 + (4 * mr1 + koct)] : 0.0f;
    wsu[WS_AU + idx] = packh(w0, w1);
  }
  for (int idx = tid0; idx < 10160; idx += stride) {  // Wc [col][grow]
    int grow = idx % 80, col = idx / 80;
    int u = grow >> 2, ty = grow & 3;
    ws[WS_WCD + idx] = W_ih1[(ty * 20 + u) * 127 + col];
  }
}

// V11 = r10 + register-resident MFMA B operands (k-slot co-design).
// r10 post-mortem: issue/latency-bound; the h/lhlc LDS round-trip sat on
// the step critical path and cost 13 LDS instr + 8.3M conflict cycles per
// dispatch. New k-mapping makes each lane's B-fragment exactly its own
// D-output values -> hsh/lsh deleted, conflicts -> ~0, critical path is
// now MFMA -> act -> pack -> MFMA. Same FP ops otherwise; only MFMA
// k-summation order changes (few-ulp; absmax must stay ~0.0859).
__global__ __launch_bounds__(256, 1) void sampler_kernel(
    const float* __restrict__ mu, const float* __restrict__ log_var,
    const float* __restrict__ ws,
    const float* __restrict__ b_ih1, const float* __restrict__ b_hh1,
    const float* __restrict__ W_hh2,
    const float* __restrict__ b_ih2, const float* __restrict__ b_hh2,
    float* __restrict__ out) {
  __shared__ float WcL[10160];                       // [col][grow80] f32

  const int tid  = threadIdx.x;
  const int lane = tid & 63;
  const int sub  = lane >> 4;                        // 0..3
  const int el   = lane & 15;
  const int elem = blockIdx.x * 64 + (tid >> 6) * 16 + el;

  // stage Wc (f32, exact)
  for (int i = tid; i < 10160; i += 256) WcL[i] = ws[WS_WCD + i];

  // A-fragments (constant across loop): coalesced 16B/lane global loads
  const uint32_t* wsu = (const uint32_t*)ws;
  f16x8 aw[5], au0, au1;
#pragma unroll
  for (int m = 0; m < 5; ++m)
    aw[m] = *(const f16x8*)(wsu + WS_AW + (m * 64 + lane) * 4);
  au0 = *(const f16x8*)(wsu + WS_AU + lane * 4);
  au1 = *(const f16x8*)(wsu + WS_AU + (64 + lane) * 4);

  __syncthreads();   // the only barrier: WcL ready

  const float* mrow = mu + (size_t)elem * LDIM;

  // per-lane LSTM2 constants for MY 4 d2 rows j = 4*sub + r (&7 aliases
  // the garbage sub2/3 lanes into range; unread, as before).
  float wa[4], wb[4], bb2[4], Sc[4], Ac[4], Bc[4];
#pragma unroll
  for (int r = 0; r < 4; ++r) {
    const int j = (4 * sub + r) & 7;
    wa[r]  = W_hh2[2 * j];
    wb[r]  = W_hh2[2 * j + 1];
    bb2[r] = b_ih2[j] + b_hh2[j];
    const bool isT = (j == 4) || (j == 5);           // tanh rows
    Sc[r] = isT ?  2.885390081777926f : -1.442695040888963f;
    Ac[r] = isT ?  1.0f : 0.0f;
    Bc[r] = isT ? -2.0f : 1.0f;
  }

  // first_input (replicated on the 4 sub-lanes of each elem; bit-identical)
  float eps0 = eps_val(0, elem);
  float m0 = mrow[0];
  float fi = fmaf(eps0, fexp(0.5f * log_var[(size_t)elem * LDIM]), m0);

  // acc = C-operand of the gates MFMA: exact-f32 input-projection prefix.
  f32x4 acc[5];
#pragma unroll
  for (int m = 0; m < 5; ++m) {
    f32x4 w0 = *(const f32x4*)&WcL[16 * m + 4 * sub];
#pragma unroll
    for (int r = 0; r < 4; ++r) {
      const int grow = 16 * m + 4 * sub + r;
      const int g = (grow & 3) * 20 + (grow >> 2);
      acc[m][r] = fmaf(fi, w0[r], b_ih1[g] + b_hh1[g]);
    }
  }

  float cst[5];
#pragma unroll
  for (int m = 0; m < 5; ++m) cst[m] = 0.0f;
  float h2a = 0.0f, h2b = 0.0f, c2a = 0.0f, c2b = 0.0f;

  float* out_mu = out;
  float* out_lv = out + (size_t)BATCH * LDIM;
  float* out_sp = out + 2 * (size_t)BATCH * LDIM;
  const size_t rowoff = (size_t)elem * LDIM;
  if (sub == 0)      { out_mu[rowoff] = 0.0f; out_lv[rowoff] = 1.0f; }
  else if (sub == 1) { out_sp[rowoff] = fi; }

  const f32x4 z4 = {0.0f, 0.0f, 0.0f, 0.0f};
  const u32x4 zu = {0u, 0u, 0u, 0u};
  // register-resident B operands (k-slot co-design)
  f16x8 bh  = __builtin_bit_cast(f16x8, zu);         // h(0) = 0
  f16x8 blA = __builtin_bit_cast(f16x8, zu);         // lhlc(prev), MFMA0
  f16x8 blB = __builtin_bit_cast(f16x8, zu);         // lhlc(prev), MFMA1

  float xm_pref = m0;
  float eps4 = 0.0f, eps_old = 0.0f;

  // LSTM2-finish for step e (register B operands; sub-split gates as r10).
  auto lstm2_finish = [&](f16x8 bl0, f16x8 bl1, float eps_t, int e) {
    f32x4 d2 = __builtin_amdgcn_mfma_f32_16x16x32_f16(au0, bl0, z4, 0, 0, 0);
    d2 = __builtin_amdgcn_mfma_f32_16x16x32_f16(au1, bl1, d2, 0, 0, 0);
    float act[4];
#pragma unroll
    for (int r = 0; r < 4; ++r) {
      float g  = fmaf(h2a, wa[r], fmaf(h2b, wb[r], bb2[r])) + d2[r];
      float rc = frcp(1.0f + fexp2(Sc[r] * g));
      act[r] = fmaf(Bc[r], rc, Ac[r]);
    }
    float x0 = __shfl_xor(act[0], 16, 64);
    float x1 = __shfl_xor(act[1], 16, 64);
    float x2 = __shfl_xor(act[2], 16, 64);
    float x3 = __shfl_xor(act[3], 16, 64);
    const bool s1 = (sub & 1);
    float i20 = s1 ? x0 : act[0], i21 = s1 ? x1 : act[1];
    float f20 = s1 ? x2 : act[2], f21 = s1 ? x3 : act[3];
    float t20 = s1 ? act[0] : x0, t21 = s1 ? act[1] : x1;
    float o20 = s1 ? act[2] : x2, o21 = s1 ? act[3] : x3;
    c2a = fmaf(f20, c2a, i20 * t20);
    c2b = fmaf(f21, c2b, i21 * t21);
    h2a = o20 * tanhx(c2a);
    h2b = o21 * tanhx(c2b);
    if (sub == 0) {
      out_mu[rowoff + e] = h2a;
      out_lv[rowoff + e] = h2b;
    } else if (sub == 1) {
      out_sp[rowoff + e] = fmaf(eps_t, fexp(0.5f * h2b), h2a);
    }
  };

  for (int t = 1; t < LDIM; ++t) {
    float xm = xm_pref;
    xm_pref = mrow[t];

    // eps ring: refresh covers {t..t+3}; shadow the old window since the
    // pipelined consumer (e = t-1) is one step behind the producer.
    const bool refresh = ((t - 1) & 3) == 0;
    if (refresh) { eps_old = eps4; eps4 = eps_val(t + sub, elem); }

    // ---- acc prefix (exact f32, r10-identical ordering) ----
    if (t >= 2) {
      if (t == 2) {
        float d0 = m0 - fi;   // col 0 switches first_input -> mu[:,0]
#pragma unroll
        for (int m = 0; m < 5; ++m) {
          f32x4 w0 = *(const f32x4*)&WcL[16 * m + 4 * sub];
#pragma unroll
          for (int r = 0; r < 4; ++r) acc[m][r] = fmaf(d0, w0[r], acc[m][r]);
        }
      }
#pragma unroll
      for (int m = 0; m < 5; ++m) {
        f32x4 wc = *(const f32x4*)&WcL[(t - 1) * 80 + 16 * m + 4 * sub];
#pragma unroll
        for (int r = 0; r < 4; ++r) acc[m][r] = fmaf(xm, wc[r], acc[m][r]);
      }
    }

    // ---- LSTM2 finish for e = t-1 (pipelined, register B operands) ----
    if (t >= 2) {
      float src = refresh ? eps_old : eps4;
      float eps_t = __shfl(src, ((t - 2) & 3) * 16 + el, 64);
      lstm2_finish(blA, blB, eps_t, t - 1);
    }

    // ---- gates = Whh @ h^T + acc : 5 MFMA (B = register bh) ----
    f32x4 d[5];
#pragma unroll
    for (int m = 0; m < 5; ++m)
      d[m] = __builtin_amdgcn_mfma_f32_16x16x32_f16(aw[m], bh, acc[m], 0, 0, 0);

    // ---- activations + cell (lane owns unit 4m+sub, all 4 types) ----
    float hk[5], lh[5], lc[5];
#pragma unroll
    for (int m = 0; m < 5; ++m) {
      float ik = sigm(d[m][0]), fk = sigm(d[m][1]);
      float gk = tanhx(d[m][2]), ok = sigm(d[m][3]);
      float cn = fmaf(fk, cst[m], ik * gk);
      cst[m] = cn;
      float h1 = ok * tanhx(cn);
      hk[m] = h1;
      lh[m] = (h1 >= 0.0f) ? h1 : 0.01f * h1;
      lc[m] = (cn >= 0.0f) ? cn : 0.01f * cn;
    }

    // ---- pack next-step B operands (pure registers, no LDS) ----
    {
      u32x4 tb;
      tb.x = packh(hk[0], hk[1]);
      tb.y = packh(hk[2], hk[3]);
      tb.z = packh(hk[4], 0.0f);
      tb.w = 0u;
      bh = __builtin_bit_cast(f16x8, tb);
      u32x4 t0;
      t0.x = packh(lh[0], lc[0]);
      t0.y = packh(lh[1], lc[1]);
      t0.z = packh(lh[2], lc[2]);
      t0.w = packh(lh[3], lc[3]);
      blA = __builtin_bit_cast(f16x8, t0);
      u32x4 t1;
      t1.x = packh(lh[4], lc[4]);
      t1.y = 0u; t1.z = 0u; t1.w = 0u;
      blB = __builtin_bit_cast(f16x8, t1);
    }
  }

  // ---- drain: LSTM2 finish for e = 127 ----
  {
    float eps_t = eps_val(127, elem);   // one direct call; bit-identical
    lstm2_finish(blA, blB, eps_t, 127);
  }
}

extern "C" void kernel_launch(void* const* d_in, const int* in_sizes, int n_in,
                              void* d_out, int out_size, void* d_ws, size_t ws_size,
                              hipStream_t stream) {
  (void)in_sizes; (void)n_in; (void)ws_size; (void)out_size;
  const float* mu      = (const float*)d_in[0];
  const float* log_var = (const float*)d_in[1];
  const float* W_ih1   = (const float*)d_in[2];
  const float* W_hh1   = (const float*)d_in[3];
  const float* b_ih1   = (const float*)d_in[4];
  const float* b_hh1   = (const float*)d_in[5];
  const float* W_ih2   = (const float*)d_in[6];
  const float* W_hh2   = (const float*)d_in[7];
  const float* b_ih2   = (const float*)d_in[8];
  const float* b_hh2   = (const float*)d_in[9];
  float* out = (float*)d_out;
  float* ws  = (float*)d_ws;   // needs 11952 dwords = 47.8 KB

  repack_kernel<<<dim3(8), dim3(256), 0, stream>>>(W_ih1, W_hh1, W_ih2, ws);
  dim3 grid(BATCH / 64), block(256);   // 4 waves/block, 16 elems/wave
  sampler_kernel<<<grid, block, 0, stream>>>(mu, log_var, ws, b_ih1, b_hh1,
                                             W_hh2, b_ih2, b_hh2, out);
}

// Round 12
// 292.087 us; speedup vs baseline: 1.1531x; 1.0451x over previous
//
#include <hip/hip_runtime.h>
#include <stdint.h>
#include <math.h>

#define BATCH 32768
#define LDIM 128
#define HID 20

// ws layout (dword offsets):
//   WS_AW  u32 [m5][lane64][q4]   = 1280   A-fragments of Whh1 (f16, PRE-SCALED)
//   WS_AU  u32 [ks2][lane64][q4]  = 512    A-fragments of W_ih2 (f16, PRE-SCALED)
//   WS_WCD f32 [col127][grow80]   = 10160  W_ih1 cols (f32, PRE-SCALED)
#define WS_AW  0
#define WS_AU  1280
#define WS_WCD 1792
#define WS_TOTAL 11952

// activation scale constants folded into weights (V12):
//   sigmoid rows: s = -log2(e)   -> act = frcp(1+exp2(x'))
//   tanh rows:    s = +2*log2(e) -> act = fmaf(-2, frcp(1+exp2(x')), 1)
#define SC_SIG  (-1.442695040888963f)
#define SC_TANH ( 2.885390081777926f)

// =====================================================================
// eps: jax.random.normal(key(42), (128,32768), f32), partitionable
// threefry (counters (0,n), output o0^o1) — VERIFIED PASSING. Do not touch.
// =====================================================================

__device__ __forceinline__ void threefry2x32(uint32_t x0, uint32_t x1,
                                             uint32_t& o0, uint32_t& o1) {
  const uint32_t k0 = 0u, k1 = 42u;
  const uint32_t k2 = k0 ^ k1 ^ 0x1BD11BDAu;
  uint32_t v0 = x0 + k0, v1 = x1 + k1;
#define TF_R(r) { v0 += v1; v1 = (v1 << (r)) | (v1 >> (32 - (r))); v1 ^= v0; }
  TF_R(13) TF_R(15) TF_R(26) TF_R(6)
  v0 += k1; v1 += k2 + 1u;
  TF_R(17) TF_R(29) TF_R(16) TF_R(24)
  v0 += k2; v1 += k0 + 2u;
  TF_R(13) TF_R(15) TF_R(26) TF_R(6)
  v0 += k0; v1 += k1 + 3u;
  TF_R(17) TF_R(29) TF_R(16) TF_R(24)
  v0 += k1; v1 += k2 + 4u;
  TF_R(13) TF_R(15) TF_R(26) TF_R(6)
  v0 += k2; v1 += k0 + 5u;
#undef TF_R
  o0 = v0; o1 = v1;
}

__device__ __forceinline__ float erfinv_xla_f32(float x) {
  float t = __fmul_rn(x, x);
  float w = -(float)log1p(-(double)t);   // correctly-rounded f32 log1p
  float p;
  if (w < 5.0f) {
    w = __fadd_rn(w, -2.5f);
    p = 2.81022636e-08f;
    p = __fadd_rn(__fmul_rn(p, w), 3.43273939e-07f);
    p = __fadd_rn(__fmul_rn(p, w), -3.5233877e-06f);
    p = __fadd_rn(__fmul_rn(p, w), -4.39150654e-06f);
    p = __fadd_rn(__fmul_rn(p, w), 0.00021858087f);
    p = __fadd_rn(__fmul_rn(p, w), -0.00125372503f);
    p = __fadd_rn(__fmul_rn(p, w), -0.00417768164f);
    p = __fadd_rn(__fmul_rn(p, w), 0.246640727f);
    p = __fadd_rn(__fmul_rn(p, w), 1.50140941f);
  } else {
    w = __fadd_rn(__fsqrt_rn(w), -3.0f);
    p = -0.000200214257f;
    p = __fadd_rn(__fmul_rn(p, w), 0.000100950558f);
    p = __fadd_rn(__fmul_rn(p, w), 0.00134934322f);
    p = __fadd_rn(__fmul_rn(p, w), -0.00367342844f);
    p = __fadd_rn(__fmul_rn(p, w), 0.00573950773f);
    p = __fadd_rn(__fmul_rn(p, w), -0.0076224613f);
    p = __fadd_rn(__fmul_rn(p, w), 0.00943887047f);
    p = __fadd_rn(__fmul_rn(p, w), 1.00167406f);
    p = __fadd_rn(__fmul_rn(p, w), 2.83297682f);
  }
  return __fmul_rn(p, x);
}

__device__ __forceinline__ float eps_val(int t, int b) {
  uint32_t n = (uint32_t)t * 32768u + (uint32_t)b;
  uint32_t o0, o1;
  threefry2x32(0u, n, o0, o1);
  uint32_t bits = o0 ^ o1;
  const float lo    = __uint_as_float(0xBF7FFFFFu);
  const float sqrt2 = __uint_as_float(0x3FB504F3u);
  float f = __fadd_rn(__uint_as_float((bits >> 9) | 0x3F800000u), -1.0f);
  float u = __fadd_rn(__fmul_rn(f, 2.0f), lo);
  u = fmaxf(u, lo);
  return __fmul_rn(sqrt2, erfinv_xla_f32(u));
}

__device__ __forceinline__ float fexp2(float x) { return __builtin_amdgcn_exp2f(x); }
__device__ __forceinline__ float frcp(float x)  { return __builtin_amdgcn_rcpf(x); }
__device__ __forceinline__ float fexp(float x)  { return fexp2(1.442695040888963f * x); }
__device__ __forceinline__ float tanhx(float x) { return 1.0f - 2.0f * frcp(1.0f + fexp2(2.885390081777926f * x)); }

typedef _Float16 f16x8 __attribute__((ext_vector_type(8)));
typedef _Float16 f16x2 __attribute__((ext_vector_type(2)));
typedef float    f32x4 __attribute__((ext_vector_type(4)));
typedef uint32_t u32x4 __attribute__((ext_vector_type(4)));

__device__ __forceinline__ uint32_t packh(float x, float y) {
  f16x2 p;
  p.x = (_Float16)x;
  p.y = (_Float16)y;
  return __builtin_bit_cast(uint32_t, p);
}

// =====================================================================
// repack (V12): k-slot co-design as r11 + activation scales folded in.
//   gates MFMA: B k-slot sub*8+m <-> h of unit 4m+sub; A rows scaled by
//               SC_SIG (ty 0,1,3) / SC_TANH (ty 2).
//   LSTM2 MFMA: B k-slot ks*32+sub*8+q <-> (m=ks*4+(q>>1), s=q&1); A rows
//               j scaled by SC_TANH for j in {4,5}, else SC_SIG.
//   Wc: f32, grow-ordered, scaled by the same per-type constant (the acc
//       prefix then tracks s*acc exactly in f32).
// =====================================================================
__global__ void repack_kernel(const float* __restrict__ W_ih1,
                              const float* __restrict__ W_hh1,
                              const float* __restrict__ W_ih2,
                              float* __restrict__ ws) {
  uint32_t* wsu = (uint32_t*)ws;
  const int stride = gridDim.x * blockDim.x;
  const int tid0 = blockIdx.x * blockDim.x + threadIdx.x;
  for (int idx = tid0; idx < 1280; idx += stride) {   // A_whh [m][l][q]
    int q = idx & 3, l = (idx >> 2) & 63, m = idx >> 8;
    int rA = l & 15, koct = l >> 4;
    int ty = rA & 3, u = 4 * m + (rA >> 2);
    float s = (ty == 2) ? SC_TANH : SC_SIG;
    int k0 = koct * 8 + 2 * q, k1 = k0 + 1;
    int mm0 = k0 & 7, mm1 = k1 & 7;                   // k-slot within octet
    float w0 = (mm0 < 5) ? s * W_hh1[(ty * 20 + u) * 20 + (4 * mm0 + koct)] : 0.0f;
    float w1 = (mm1 < 5) ? s * W_hh1[(ty * 20 + u) * 20 + (4 * mm1 + koct)] : 0.0f;
    wsu[WS_AW + idx] = packh(w0, w1);
  }
  for (int idx = tid0; idx < 512; idx += stride) {    // A_u [ks][l][q]
    int q = idx & 3, l = (idx >> 2) & 63, ks = idx >> 8;
    int j = l & 15, koct = l >> 4;
    float s = (j == 4 || j == 5) ? SC_TANH : SC_SIG;
    int qq0 = 2 * q, qq1 = 2 * q + 1;                 // slot within octet
    int mr0 = ks * 4 + (qq0 >> 1), mr1 = ks * 4 + (qq1 >> 1);
    float w0 = (j < 8 && mr0 < 5)
                   ? s * W_ih2[j * 40 + (qq0 & 1) * 20 + (4 * mr0 + koct)] : 0.0f;
    float w1 = (j < 8 && mr1 < 5)
                   ? s * W_ih2[j * 40 + (qq1 & 1) * 20 + (4 * mr1 + koct)] : 0.0f;
    wsu[WS_AU + idx] = packh(w0, w1);
  }
  for (int idx = tid0; idx < 10160; idx += stride) {  // Wc [col][grow]
    int grow = idx % 80, col = idx / 80;
    int u = grow >> 2, ty = grow & 3;
    float s = (ty == 2) ? SC_TANH : SC_SIG;
    ws[WS_WCD + idx] = s * W_ih1[(ty * 20 + u) * 127 + col];
  }
}

// V12 = r11 + issue-stream cuts (r11 post-mortem: VALU-issue-bound, 78%
// busy, 1770 cy/wave-step):
//   1. activation scales folded into weights (-~24 v_mul/step)
//   2. leaky = fmax(x, 0.01x)  (bit-identical, -10 ops)
//   3. symmetric i*t products in LSTM2 (-4 cndmask)
//   4. Wc column prefetched one iteration ahead (ds_read latency hidden)
__global__ __launch_bounds__(256, 1) void sampler_kernel(
    const float* __restrict__ mu, const float* __restrict__ log_var,
    const float* __restrict__ ws,
    const float* __restrict__ b_ih1, const float* __restrict__ b_hh1,
    const float* __restrict__ W_hh2,
    const float* __restrict__ b_ih2, const float* __restrict__ b_hh2,
    float* __restrict__ out) {
  __shared__ float WcL[10160];                       // [col][grow80] f32 scaled

  const int tid  = threadIdx.x;
  const int lane = tid & 63;
  const int sub  = lane >> 4;                        // 0..3
  const int el   = lane & 15;
  const int elem = blockIdx.x * 64 + (tid >> 6) * 16 + el;

  // stage Wc (f32, scaled)
  for (int i = tid; i < 10160; i += 256) WcL[i] = ws[WS_WCD + i];

  // A-fragments (constant across loop): coalesced 16B/lane global loads
  const uint32_t* wsu = (const uint32_t*)ws;
  f16x8 aw[5], au0, au1;
#pragma unroll
  for (int m = 0; m < 5; ++m)
    aw[m] = *(const f16x8*)(wsu + WS_AW + (m * 64 + lane) * 4);
  au0 = *(const f16x8*)(wsu + WS_AU + lane * 4);
  au1 = *(const f16x8*)(wsu + WS_AU + (64 + lane) * 4);

  __syncthreads();   // the only barrier: WcL ready

  const float* mrow = mu + (size_t)elem * LDIM;

  // per-lane LSTM2 constants for MY 4 d2 rows j = 4*sub + r (&7 aliases
  // garbage sub2/3 lanes into range; unread). Weights/bias pre-scaled.
  float wa[4], wb[4], bb2[4], Ac[4], Bc[4];
#pragma unroll
  for (int r = 0; r < 4; ++r) {
    const int j = (4 * sub + r) & 7;
    const bool isT = (j == 4) || (j == 5);           // tanh rows
    const float s = isT ? SC_TANH : SC_SIG;
    wa[r]  = s * W_hh2[2 * j];
    wb[r]  = s * W_hh2[2 * j + 1];
    bb2[r] = s * (b_ih2[j] + b_hh2[j]);
    Ac[r] = isT ?  1.0f : 0.0f;
    Bc[r] = isT ? -2.0f : 1.0f;
  }

  // first_input (replicated on the 4 sub-lanes of each elem; bit-identical)
  float eps0 = eps_val(0, elem);
  float m0 = mrow[0];
  float fi = fmaf(eps0, fexp(0.5f * log_var[(size_t)elem * LDIM]), m0);

  // acc = C-operand of gates MFMA: exact-f32 (scaled) input-projection
  // prefix; bias scaled to match the folded weight scale.
  f32x4 acc[5];
#pragma unroll
  for (int m = 0; m < 5; ++m) {
    f32x4 w0 = *(const f32x4*)&WcL[16 * m + 4 * sub];
#pragma unroll
    for (int r = 0; r < 4; ++r) {
      const int grow = 16 * m + 4 * sub + r;
      const int ty = grow & 3;
      const int g = ty * 20 + (grow >> 2);
      const float s = (ty == 2) ? SC_TANH : SC_SIG;
      acc[m][r] = fmaf(fi, w0[r], s * (b_ih1[g] + b_hh1[g]));
    }
  }

  float cst[5];
#pragma unroll
  for (int m = 0; m < 5; ++m) cst[m] = 0.0f;
  float h2a = 0.0f, h2b = 0.0f, c2a = 0.0f, c2b = 0.0f;

  float* out_mu = out;
  float* out_lv = out + (size_t)BATCH * LDIM;
  float* out_sp = out + 2 * (size_t)BATCH * LDIM;
  const size_t rowoff = (size_t)elem * LDIM;
  if (sub == 0)      { out_mu[rowoff] = 0.0f; out_lv[rowoff] = 1.0f; }
  else if (sub == 1) { out_sp[rowoff] = fi; }

  const f32x4 z4 = {0.0f, 0.0f, 0.0f, 0.0f};
  const u32x4 zu = {0u, 0u, 0u, 0u};
  // register-resident B operands (k-slot co-design)
  f16x8 bh  = __builtin_bit_cast(f16x8, zu);         // h(0) = 0
  f16x8 blA = __builtin_bit_cast(f16x8, zu);         // lhlc(prev), MFMA0
  f16x8 blB = __builtin_bit_cast(f16x8, zu);         // lhlc(prev), MFMA1

  float xm_pref = m0;
  float eps4 = 0.0f, eps_old = 0.0f;

  // Wc column prefetch: wc holds col (t-1) at the top of iteration t.
  f32x4 wc[5];
#pragma unroll
  for (int m = 0; m < 5; ++m)
    wc[m] = *(const f32x4*)&WcL[80 + 16 * m + 4 * sub];   // col 1 (for t=2)

  // LSTM2-finish for step e (pre-scaled rows; symmetric i*t products).
  auto lstm2_finish = [&](f16x8 bl0, f16x8 bl1, float eps_t, int e) {
    f32x4 d2 = __builtin_amdgcn_mfma_f32_16x16x32_f16(au0, bl0, z4, 0, 0, 0);
    d2 = __builtin_amdgcn_mfma_f32_16x16x32_f16(au1, bl1, d2, 0, 0, 0);
    float act[4];
#pragma unroll
    for (int r = 0; r < 4; ++r) {
      float g  = fmaf(h2a, wa[r], fmaf(h2b, wb[r], bb2[r])) + d2[r];
      float rc = frcp(1.0f + fexp2(g));
      act[r] = fmaf(Bc[r], rc, Ac[r]);
    }
    float x0 = __shfl_xor(act[0], 16, 64);
    float x1 = __shfl_xor(act[1], 16, 64);
    float x2 = __shfl_xor(act[2], 16, 64);
    float x3 = __shfl_xor(act[3], 16, 64);
    // i*t products are commutative -> identical on both subs, no select
    float p0 = act[0] * x0;
    float p1 = act[1] * x1;
    const bool s1 = (sub & 1);
    float f20 = s1 ? x2 : act[2], f21 = s1 ? x3 : act[3];
    float o20 = s1 ? act[2] : x2, o21 = s1 ? act[3] : x3;
    c2a = fmaf(f20, c2a, p0);
    c2b = fmaf(f21, c2b, p1);
    h2a = o20 * tanhx(c2a);
    h2b = o21 * tanhx(c2b);
    if (sub == 0) {
      out_mu[rowoff + e] = h2a;
      out_lv[rowoff + e] = h2b;
    } else if (sub == 1) {
      out_sp[rowoff + e] = fmaf(eps_t, fexp(0.5f * h2b), h2a);
    }
  };

  for (int t = 1; t < LDIM; ++t) {
    float xm = xm_pref;
    xm_pref = mrow[t];

    // eps ring: refresh covers {t..t+3}; shadow the old window since the
    // pipelined consumer (e = t-1) is one step behind the producer.
    const bool refresh = ((t - 1) & 3) == 0;
    if (refresh) { eps_old = eps4; eps4 = eps_val(t + sub, elem); }

    // ---- acc prefix (exact f32, scaled; uses wc preloaded last iter) ----
    if (t >= 2) {
      if (t == 2) {
        float d0 = m0 - fi;   // col 0 switches first_input -> mu[:,0]
#pragma unroll
        for (int m = 0; m < 5; ++m) {
          f32x4 w0 = *(const f32x4*)&WcL[16 * m + 4 * sub];
#pragma unroll
          for (int r = 0; r < 4; ++r) acc[m][r] = fmaf(d0, w0[r], acc[m][r]);
        }
      }
#pragma unroll
      for (int m = 0; m < 5; ++m) {
#pragma unroll
        for (int r = 0; r < 4; ++r) acc[m][r] = fmaf(xm, wc[m][r], acc[m][r]);
      }
    }

    // ---- prefetch next column (col t, used at t+1); latency hidden
    //      under the remainder of this iteration ----
    {
      const int tc = (t < 127) ? t : 126;
#pragma unroll
      for (int m = 0; m < 5; ++m)
        wc[m] = *(const f32x4*)&WcL[tc * 80 + 16 * m + 4 * sub];
    }

    // ---- LSTM2 finish for e = t-1 (pipelined, register B operands) ----
    if (t >= 2) {
      float src = refresh ? eps_old : eps4;
      float eps_t = __shfl(src, ((t - 2) & 3) * 16 + el, 64);
      lstm2_finish(blA, blB, eps_t, t - 1);
    }

    // ---- gates = Whh @ h^T + acc : 5 MFMA (B = register bh) ----
    f32x4 d[5];
#pragma unroll
    for (int m = 0; m < 5; ++m)
      d[m] = __builtin_amdgcn_mfma_f32_16x16x32_f16(aw[m], bh, acc[m], 0, 0, 0);

    // ---- activations + cell (scales pre-folded into the MFMA rows) ----
    float hk[5], lh[5], lc[5];
#pragma unroll
    for (int m = 0; m < 5; ++m) {
      float ik = frcp(1.0f + fexp2(d[m][0]));
      float fk = frcp(1.0f + fexp2(d[m][1]));
      float gk = fmaf(-2.0f, frcp(1.0f + fexp2(d[m][2])), 1.0f);
      float ok = frcp(1.0f + fexp2(d[m][3]));
      float cn = fmaf(fk, cst[m], ik * gk);
      cst[m] = cn;
      float h1 = ok * tanhx(cn);
      hk[m] = h1;
      lh[m] = fmaxf(h1, 0.01f * h1);                 // == leaky_relu (exact)
      lc[m] = fmaxf(cn, 0.01f * cn);
    }

    // ---- pack next-step B operands (pure registers, no LDS) ----
    {
      u32x4 tb;
      tb.x = packh(hk[0], hk[1]);
      tb.y = packh(hk[2], hk[3]);
      tb.z = packh(hk[4], 0.0f);
      tb.w = 0u;
      bh = __builtin_bit_cast(f16x8, tb);
      u32x4 t0;
      t0.x = packh(lh[0], lc[0]);
      t0.y = packh(lh[1], lc[1]);
      t0.z = packh(lh[2], lc[2]);
      t0.w = packh(lh[3], lc[3]);
      blA = __builtin_bit_cast(f16x8, t0);
      u32x4 t1;
      t1.x = packh(lh[4], lc[4]);
      t1.y = 0u; t1.z = 0u; t1.w = 0u;
      blB = __builtin_bit_cast(f16x8, t1);
    }
  }

  // ---- drain: LSTM2 finish for e = 127 ----
  {
    float eps_t = eps_val(127, elem);   // one direct call; bit-identical
    lstm2_finish(blA, blB, eps_t, 127);
  }
}

extern "C" void kernel_launch(void* const* d_in, const int* in_sizes, int n_in,
                              void* d_out, int out_size, void* d_ws, size_t ws_size,
                              hipStream_t stream) {
  (void)in_sizes; (void)n_in; (void)ws_size; (void)out_size;
  const float* mu      = (const float*)d_in[0];
  const float* log_var = (const float*)d_in[1];
  const float* W_ih1   = (const float*)d_in[2];
  const float* W_hh1   = (const float*)d_in[3];
  const float* b_ih1   = (const float*)d_in[4];
  const float* b_hh1   = (const float*)d_in[5];
  const float* W_ih2   = (const float*)d_in[6];
  const float* W_hh2   = (const float*)d_in[7];
  const float* b_ih2   = (const float*)d_in[8];
  const float* b_hh2   = (const float*)d_in[9];
  float* out = (float*)d_out;
  float* ws  = (float*)d_ws;   // needs 11952 dwords = 47.8 KB

  repack_kernel<<<dim3(8), dim3(256), 0, stream>>>(W_ih1, W_hh1, W_ih2, ws);
  dim3 grid(BATCH / 64), block(256);   // 4 waves/block, 16 elems/wave
  sampler_kernel<<<grid, block, 0, stream>>>(mu, log_var, ws, b_ih1, b_hh1,
                                             W_hh2, b_ih2, b_hh2, out);
}